// Round 1
// baseline (7336.214 us; speedup 1.0000x reference)
//
#include <hip/hip_runtime.h>
#include <stdint.h>

// LSTM  B=128, S=256, I=1024, H=1024
// Phase 1: gates_x = x @ Wx^T + b   (parallel GEMM, bf16 MFMA, m97-style)  -- unchanged
// Phase 2: persistent cooperative kernel, 8 launches x 32 steps.
//   256 blocks (1/CU) x 512 threads. Block = (16 h-cols x 4 gates) x (32 batch rows).
//   Wh slice lives in VGPRs (breg[16] per wave) for the whole launch; h staged via
//   global_load_lds; one device-scope grid barrier per step (custom counter).
//
// Workspace layout (bytes):
//   Xc    bf16 [S*B][I]      67,108,864   @ 0          (row m = s*128 + b)
//   Whp   bf16 [4H][H]        8,388,608   @ 67,108,864 (n = gate*1024 + h; f,i,g,o)
//   Wxp   bf16 [4H][I]        8,388,608   @ 75,497,472
//   biasp f32  [4H]              16,384   @ 83,886,080
//   h2    bf16 2*[128][1024]    524,288   @ 83,902,464 (ping-pong)
//   cws   f32  [128][1024]      524,288   @ 84,426,752
//   gx    bf16 [4096][4096]  33,554,432   @ 84,951,040 (one 32-step chunk)
// total 118,505,472

typedef unsigned short u16;
typedef unsigned int u32;
typedef __bf16 bf16x8 __attribute__((ext_vector_type(8)));
typedef float f32x4 __attribute__((ext_vector_type(4)));
typedef float f32x16 __attribute__((ext_vector_type(16)));

__device__ unsigned g_bar;  // grid-barrier counter (monotonic per replay; zeroed in pack_b)

__device__ __forceinline__ u16 f2bf(float f) {
  u32 u = __builtin_bit_cast(u32, f);
  u = (u + 0x7fffu + ((u >> 16) & 1u)) >> 16;
  return (u16)u;
}
__device__ __forceinline__ float bf2f(u16 s) {
  u32 u = ((u32)s) << 16;
  return __builtin_bit_cast(float, u);
}
__device__ __forceinline__ u32 pack2bf(float a, float b) {
  return (u32)f2bf(a) | ((u32)f2bf(b) << 16);
}

// async global -> LDS, 16B per lane. LDS dest must be wave-uniform base + lane*16.
__device__ __forceinline__ void gl2lds16(const void* gptr, void* lptr) {
  __builtin_amdgcn_global_load_lds(
      (__attribute__((address_space(1))) void*)(uintptr_t)gptr,
      (__attribute__((address_space(3))) void*)(uintptr_t)lptr, 16, 0, 0);
}

__device__ __forceinline__ float sigm(float x) { return 1.f / (1.f + __expf(-x)); }
__device__ __forceinline__ float tanh_f(float x) { return 2.f / (1.f + __expf(-2.f * x)) - 1.f; }

// device-scope grid barrier: all blocks arrive; optionally wait for `target` arrivals.
__device__ __forceinline__ void grid_sync(unsigned target, bool wait) {
  __syncthreads();  // drains this block's global stores (vmcnt 0 before s_barrier)
  if (threadIdx.x == 0) {
    __threadfence();  // agent-scope release: write back L2 (cross-XCD visibility)
    __hip_atomic_fetch_add(&g_bar, 1u, __ATOMIC_RELEASE, __HIP_MEMORY_SCOPE_AGENT);
    if (wait) {
      unsigned v;
      do {
        __builtin_amdgcn_s_sleep(2);
        v = __hip_atomic_load(&g_bar, __ATOMIC_ACQUIRE, __HIP_MEMORY_SCOPE_AGENT);
      } while (v < target);
      __threadfence();  // agent-scope acquire: invalidate L1/L2 before h reads
    }
  }
  if (wait) __syncthreads();
}

// ---------------- pack / convert kernels ----------------

// x [B][S][I] f32 -> Xc bf16 [S*B][I] with row m = s*128 + b
__global__ __launch_bounds__(256) void convert_x(const float* __restrict__ x, u16* __restrict__ Xc) {
  int t = blockIdx.x * 256 + threadIdx.x;  // 0..4194303
  int i8 = t & 127;
  int s = (t >> 7) & 255;
  int b = t >> 15;
  const float4* src = (const float4*)(x + (((b << 8) + s) << 10) + (i8 << 3));
  float4 a = src[0], c = src[1];
  uint4 o;
  o.x = pack2bf(a.x, a.y); o.y = pack2bf(a.z, a.w);
  o.z = pack2bf(c.x, c.y); o.w = pack2bf(c.z, c.w);
  *(uint4*)(Xc + (((s << 7) + b) << 10) + (i8 << 3)) = o;
}

__global__ __launch_bounds__(256) void pack_w(const float* __restrict__ Wf, const float* __restrict__ Wi,
                                              const float* __restrict__ Wc, const float* __restrict__ Wo,
                                              u16* __restrict__ Whp, u16* __restrict__ Wxp) {
  int t = blockIdx.x * 256 + threadIdx.x;  // 0..524287
  int k8 = t & 127, n = t >> 7;
  int g = n >> 10, h = n & 1023;
  const float* W = (g == 0) ? Wf : (g == 1) ? Wi : (g == 2) ? Wc : Wo;
  const float4* ph = (const float4*)(W + h * 2048 + (k8 << 3));
  float4 a = ph[0], b = ph[1];
  uint4 oh;
  oh.x = pack2bf(a.x, a.y); oh.y = pack2bf(a.z, a.w);
  oh.z = pack2bf(b.x, b.y); oh.w = pack2bf(b.z, b.w);
  *(uint4*)(Whp + n * 1024 + (k8 << 3)) = oh;
  const float4* px = (const float4*)(W + h * 2048 + 1024 + (k8 << 3));
  float4 c = px[0], d = px[1];
  uint4 ox;
  ox.x = pack2bf(c.x, c.y); ox.y = pack2bf(c.z, c.w);
  ox.z = pack2bf(d.x, d.y); ox.w = pack2bf(d.z, d.w);
  *(uint4*)(Wxp + n * 1024 + (k8 << 3)) = ox;
}

__global__ __launch_bounds__(256) void pack_b(const float* __restrict__ bf_, const float* __restrict__ bi,
                                              const float* __restrict__ bc, const float* __restrict__ bo,
                                              float* __restrict__ biasp) {
  if (blockIdx.x == 0 && threadIdx.x == 0) g_bar = 0;  // reset grid barrier each replay
  int n = blockIdx.x * 256 + threadIdx.x;  // 0..4095
  int g = n >> 10, h = n & 1023;
  const float* b = (g == 0) ? bf_ : (g == 1) ? bi : (g == 2) ? bc : bo;
  biasp[n] = b[h];
}

// ---------------- phase 1 GEMM: gx = Xc @ Wxp^T + bias ----------------
// 128x128 tile, BK=64, single LDS buffer, 2 barriers/iter (m97 structure),
// XOR swizzle (c8 ^ (row&7)) for conflict-free ds_read_b128 frag loads.
__global__ __launch_bounds__(256) void gemm_x(const u16* __restrict__ A,   // Xc [32768][1024]
                                              const u16* __restrict__ Bw,  // Wxp [4096][1024]
                                              const float* __restrict__ bias,
                                              u16* __restrict__ gx,  // [4096][4096] chunk-local
                                              int m_base) {
  __shared__ __align__(16) u16 lds_a[128 * 64];
  __shared__ __align__(16) u16 lds_b[128 * 64];
  const int tid = threadIdx.x;
  const int lane = tid & 63, q = lane >> 4, cl = lane & 15;
  const int w = tid >> 6, wm = w & 1, wn = w >> 1;
  const int m0 = m_base + blockIdx.y * 128;
  const int n0 = blockIdx.x * 128;
  f32x4 acc[4][4] = {};

  for (int it = 0; it < 16; ++it) {
    const int k0 = it * 64;
#pragma unroll
    for (int itn = 0; itn < 4; ++itn) {  // A: 1024 chunks of 16B
      int j = itn * 256 + tid;
      int row = j >> 3, c8s = (j & 7) ^ (row & 7);
      gl2lds16(A + (m0 + row) * 1024 + k0 + c8s * 8, &lds_a[j * 8]);
    }
#pragma unroll
    for (int itn = 0; itn < 4; ++itn) {  // B: 1024 chunks
      int j = itn * 256 + tid;
      int row = j >> 3, c8s = (j & 7) ^ (row & 7);
      gl2lds16(Bw + (n0 + row) * 1024 + k0 + c8s * 8, &lds_b[j * 8]);
    }
    asm volatile("s_waitcnt vmcnt(0)" ::: "memory");
    __syncthreads();
#pragma unroll
    for (int kk = 0; kk < 2; ++kk) {
      bf16x8 af[4], bfr[4];
#pragma unroll
      for (int mt = 0; mt < 4; ++mt) {
        int row = wm * 64 + mt * 16 + cl;
        int c8 = (kk * 4 + q) ^ (row & 7);
        af[mt] = *(const bf16x8*)&lds_a[row * 64 + c8 * 8];
      }
#pragma unroll
      for (int nt = 0; nt < 4; ++nt) {
        int row = wn * 64 + nt * 16 + cl;
        int c8 = (kk * 4 + q) ^ (row & 7);
        bfr[nt] = *(const bf16x8*)&lds_b[row * 64 + c8 * 8];
      }
#pragma unroll
      for (int mt = 0; mt < 4; ++mt)
#pragma unroll
        for (int nt = 0; nt < 4; ++nt)
          acc[mt][nt] = __builtin_amdgcn_mfma_f32_16x16x32_bf16(af[mt], bfr[nt], acc[mt][nt], 0, 0, 0);
    }
    __syncthreads();
  }
  // epilogue: C[m][n], m = wm*64+mt*16+q*4+r, n = wn*64+nt*16+cl
#pragma unroll
  for (int nt = 0; nt < 4; ++nt) {
    int n = n0 + wn * 64 + nt * 16 + cl;
    float bv = bias[n];
#pragma unroll
    for (int mt = 0; mt < 4; ++mt) {
#pragma unroll
      for (int r = 0; r < 4; ++r) {
        int m_loc = blockIdx.y * 128 + wm * 64 + mt * 16 + q * 4 + r;
        gx[m_loc * 4096 + n] = f2bf(acc[mt][nt][r] + bv);
      }
    }
  }
}

// ---------------- phase 2: persistent recurrent kernel (32 steps / launch) ----------------
// 256 blocks x 512 threads. Block bx: hgrp = bx&63 (h0 = 16*hgrp, n-set = 4 gates x 16 h = 64 rows
// of Whp), mq = bx>>6 (m0 = 32*mq batch rows). 8 waves: wn = w&1 (which 32 of the 64 n-rows),
// kh = w>>1 (which K-quarter of 256). Each wave holds its Wh fragment slice in registers
// (breg[16], 64 VGPR) for the entire launch. Per step: stage h (2 chunks, double-buffered,
// 16B-granule XOR swizzle), 16 x mfma_f32_32x32x16_bf16 per wave into 2 accumulator chains,
// K-partials summed via LDS pre[4][64][34], fused cell update (c-state in registers).
__global__ __launch_bounds__(512, 2) void lstm_chunk(const u16* __restrict__ Whp,  // [4096][1024]
                                                     const u16* __restrict__ gx,   // [4096][4096]
                                                     u16* __restrict__ h2,         // 2 x [128][1024]
                                                     float* __restrict__ cws,      // [128][1024]
                                                     float* __restrict__ out,      // [128][256][1024]
                                                     int s_base) {
  __shared__ __align__(16) u16 lds_a[2][4][32][128];  // [buf][kh][row][k-elems] = 64 KB
  __shared__ float pre[4][64][34];                    // [kh][n_loc][m] (pad 34: 2-way max)

  const int tid = threadIdx.x;
  const int lane = tid & 63;
  const int w = tid >> 6;   // 0..7
  const int wn = w & 1;     // n-half: rows [wn*32, wn*32+32) of the 64 Wh rows
  const int kh = w >> 1;    // K-quarter: k in [kh*256, kh*256+256)
  const int l5 = lane >> 5;
  const int r31 = lane & 31;
  const int hgrp = blockIdx.x & 63, mq = blockIdx.x >> 6;
  const int h0 = hgrp * 16, m0 = mq * 32;

  // persistent B fragments (loaded once per launch): 16 x bf16x8 = 64 VGPR
  bf16x8 breg[16];
  {
    const int n_loc = wn * 32 + r31;                       // 0..63: g*16 + hl
    const int ng = ((n_loc >> 4) << 10) + h0 + (n_loc & 15);
    const u16* wp = Whp + ng * 1024 + kh * 256 + l5 * 8;
#pragma unroll
    for (int ks = 0; ks < 16; ++ks) breg[ks] = *(const bf16x8*)(wp + ks * 16);
  }

  // cell ownership: thread -> (m=tid>>4, h=tid&15); c-state stays in a register
  const int cm = tid >> 4, chl = tid & 15;
  const int mg = m0 + cm, hg = h0 + chl;
  float creg = cws[mg * 1024 + hg];

  for (int t = 0; t < 32; ++t) {
    const int s = s_base + t;
    const u16* hin = h2 + (s & 1) * 131072;
    u16* hout = h2 + ((s + 1) & 1) * 131072;

    // prefetch gates_x for the cell update (hides L2/L3 latency under the GEMM)
    const int grow = ((s & 31) << 7) + mg;
    const u16 gxv0 = gx[grow * 4096 + hg];
    const u16 gxv1 = gx[grow * 4096 + 1024 + hg];
    const u16 gxv2 = gx[grow * 4096 + 2048 + hg];
    const u16 gxv3 = gx[grow * 4096 + 3072 + hg];

    // stage chunk 0: k-cols [q*256, q*256+128) for each quarter q; 16B-granule swizzle u^(row&15)
#pragma unroll
    for (int it = 0; it < 4; ++it) {
      const int j = it * 512 + tid;  // 0..2047 granules
      const int khs = j >> 9, row = (j >> 4) & 31, u = j & 15;
      gl2lds16(hin + (m0 + row) * 1024 + khs * 256 + ((u ^ (row & 15)) << 3),
               (u16*)lds_a + j * 8);
    }
    asm volatile("s_waitcnt vmcnt(0)" ::: "memory");
    __syncthreads();
    // stage chunk 1 into buf 1 (async; overlaps chunk-0 MFMAs)
#pragma unroll
    for (int it = 0; it < 4; ++it) {
      const int j = it * 512 + tid;
      const int khs = j >> 9, row = (j >> 4) & 31, u = j & 15;
      gl2lds16(hin + (m0 + row) * 1024 + khs * 256 + 128 + ((u ^ (row & 15)) << 3),
               (u16*)lds_a + 16384 + j * 8);
    }

    f32x16 acc0 = {}, acc1 = {};  // two chains (even/odd kstep) to cover MFMA latency
#pragma unroll
    for (int ksl = 0; ksl < 8; ++ksl) {
      const int u = ((ksl << 1) + l5) ^ (r31 & 15);
      const bf16x8 av = *(const bf16x8*)&lds_a[0][kh][r31][u << 3];
      if (ksl & 1)
        acc1 = __builtin_amdgcn_mfma_f32_32x32x16_bf16(av, breg[ksl], acc1, 0, 0, 0);
      else
        acc0 = __builtin_amdgcn_mfma_f32_32x32x16_bf16(av, breg[ksl], acc0, 0, 0, 0);
    }
    asm volatile("s_waitcnt vmcnt(0)" ::: "memory");
    __syncthreads();
#pragma unroll
    for (int ksl = 0; ksl < 8; ++ksl) {
      const int u = ((ksl << 1) + l5) ^ (r31 & 15);
      const bf16x8 av = *(const bf16x8*)&lds_a[1][kh][r31][u << 3];
      if (ksl & 1)
        acc1 = __builtin_amdgcn_mfma_f32_32x32x16_bf16(av, breg[8 + ksl], acc1, 0, 0, 0);
      else
        acc0 = __builtin_amdgcn_mfma_f32_32x32x16_bf16(av, breg[8 + ksl], acc0, 0, 0, 0);
    }

    // K-partial to LDS: C col = lane&31 (n), row = (r&3)+8*(r>>2)+4*(lane>>5) (m)
#pragma unroll
    for (int r = 0; r < 16; ++r) {
      const int m_l = (r & 3) + ((r >> 2) << 3) + (l5 << 2);
      pre[kh][wn * 32 + r31][m_l] = acc0[r] + acc1[r];
    }
    __syncthreads();

    // fused cell update: sum 4 K-partials + gates_x, activations, write h/out
    float p0 = pre[0][chl][cm] + pre[1][chl][cm] + pre[2][chl][cm] + pre[3][chl][cm] + bf2f(gxv0);
    float p1 = pre[0][16 + chl][cm] + pre[1][16 + chl][cm] + pre[2][16 + chl][cm] + pre[3][16 + chl][cm] + bf2f(gxv1);
    float p2 = pre[0][32 + chl][cm] + pre[1][32 + chl][cm] + pre[2][32 + chl][cm] + pre[3][32 + chl][cm] + bf2f(gxv2);
    float p3 = pre[0][48 + chl][cm] + pre[1][48 + chl][cm] + pre[2][48 + chl][cm] + pre[3][48 + chl][cm] + bf2f(gxv3);
    const float fg = sigm(p0), ig = sigm(p1), gg = tanh_f(p2), og = sigm(p3);
    creg = creg * fg + ig * gg;
    const float hn = tanh_f(creg) * og;
    hout[mg * 1024 + hg] = f2bf(hn);
    out[(mg * 256 + s) * 1024 + hg] = hn;

    // one grid barrier per step (last step: arrive only; kernel boundary orders the rest)
    grid_sync(256u * (unsigned)(s + 1), t != 31);
  }
  cws[mg * 1024 + hg] = creg;
}

// ---------------- launch ----------------

extern "C" void kernel_launch(void* const* d_in, const int* in_sizes, int n_in,
                              void* d_out, int out_size, void* d_ws, size_t ws_size,
                              hipStream_t stream) {
  const float* x   = (const float*)d_in[0];
  const float* Wf  = (const float*)d_in[1];
  const float* bf_ = (const float*)d_in[2];
  const float* Wi  = (const float*)d_in[3];
  const float* bi  = (const float*)d_in[4];
  const float* Wc  = (const float*)d_in[5];
  const float* bc  = (const float*)d_in[6];
  const float* Wo  = (const float*)d_in[7];
  const float* bo  = (const float*)d_in[8];
  float* out = (float*)d_out;
  char* ws = (char*)d_ws;

  const size_t NEEDED = 118505472;
  if (ws_size < NEEDED) return;  // fail cleanly (wrong output) instead of faulting

  u16*  Xc    = (u16*)(ws);
  u16*  Whp   = (u16*)(ws + 67108864);
  u16*  Wxp   = (u16*)(ws + 75497472);
  float* biasp = (float*)(ws + 83886080);
  u16*  h2    = (u16*)(ws + 83902464);   // 2 x 131072 bf16
  float* cws  = (float*)(ws + 84426752);
  u16*  gx    = (u16*)(ws + 84951040);

  // zero h (both buffers) + c
  hipMemsetAsync(ws + 83902464, 0, 1048576, stream);
  convert_x<<<16384, 256, 0, stream>>>(x, Xc);
  pack_w<<<2048, 256, 0, stream>>>(Wf, Wi, Wc, Wo, Whp, Wxp);
  pack_b<<<16, 256, 0, stream>>>(bf_, bi, bc, bo, biasp);  // also zeroes g_bar

  for (int c = 0; c < 8; ++c) {
    gemm_x<<<dim3(32, 32), 256, 0, stream>>>(Xc, Wxp, biasp, gx, c * 4096);
    int sbase = c * 32;
    void* args[6];
    args[0] = (void*)&Whp;
    args[1] = (void*)&gx;
    args[2] = (void*)&h2;
    args[3] = (void*)&cws;
    args[4] = (void*)&out;
    args[5] = (void*)&sbase;
    if (hipLaunchCooperativeKernel((const void*)lstm_chunk, dim3(256), dim3(512),
                                   args, 0, stream) != hipSuccess) {
      // fallback: plain launch. grid=256 blocks, 1/CU via __launch_bounds__(512,2)
      // => all co-resident in practice; custom barrier still works.
      lstm_chunk<<<dim3(256), dim3(512), 0, stream>>>(Whp, gx, h2, cws, out, sbase);
    }
  }
}

// Round 2
// 2150.524 us; speedup vs baseline: 3.4114x; 3.4114x over previous
//
#include <hip/hip_runtime.h>
#include <stdint.h>

// LSTM  B=128, S=256, I=1024, H=1024
// Phase 1: gates_x = x @ Wx^T + b   (parallel GEMM, bf16 MFMA, m97-style)
// Phase 2: persistent kernel, 16 launches x 16 steps. 256 blocks x 512 threads,
//   block = (16 h-cols x 4 gates) x (32 batch rows). Wh slice pinned in VGPRs.
//   Cross-block sync WITHOUT fences:
//     - h ring buffer (32 slots): a slot is written once and read once per launch,
//       so plain cached loads can never see stale L2 lines (dispatch-boundary
//       acquire handles cross-launch).
//     - h stores are relaxed agent-scope atomics (global_store sc1, write-through
//       to LLC); ring layout [hgrp][m][16] gives each block whole 128B lines.
//     - arrival: s_waitcnt vmcnt(0) + relaxed fetch_add on a per-mq counter
//       (batch quarters are independent recurrences -> 4 sync domains x 64 blocks).
//     - consumers poll the counter with relaxed agent loads. No threadfence at all.
//
// Workspace layout (bytes):
//   Xc    bf16 [S*B][I]      67,108,864   @ 0          (row m = s*128 + b)
//   Whp   bf16 [4H][H]        8,388,608   @ 67,108,864 (n = gate*1024 + h; f,i,g,o)
//   Wxp   bf16 [4H][I]        8,388,608   @ 75,497,472
//   biasp f32  [4H]              16,384   @ 83,886,080
//   hring bf16 32*[64][128][16] 8,388,608 @ 83,902,464 (slot = step mod 32)
//   cws   f32  [128][1024]      524,288   @ 92,291,072
//   gx    bf16 [2048][4096]  16,777,216   @ 92,815,360 (one 16-step chunk)
// total 109,592,576

typedef unsigned short u16;
typedef unsigned int u32;
typedef __bf16 bf16x8 __attribute__((ext_vector_type(8)));
typedef float f32x4 __attribute__((ext_vector_type(4)));
typedef float f32x16 __attribute__((ext_vector_type(16)));

__device__ unsigned g_bars[128];  // per-mq counters at g_bars[mq*32] (128B apart)

__device__ __forceinline__ u16 f2bf(float f) {
  u32 u = __builtin_bit_cast(u32, f);
  u = (u + 0x7fffu + ((u >> 16) & 1u)) >> 16;
  return (u16)u;
}
__device__ __forceinline__ float bf2f(u16 s) {
  u32 u = ((u32)s) << 16;
  return __builtin_bit_cast(float, u);
}
__device__ __forceinline__ u32 pack2bf(float a, float b) {
  return (u32)f2bf(a) | ((u32)f2bf(b) << 16);
}

// async global -> LDS, 16B per lane. LDS dest must be wave-uniform base + lane*16.
__device__ __forceinline__ void gl2lds16(const void* gptr, void* lptr) {
  __builtin_amdgcn_global_load_lds(
      (__attribute__((address_space(1))) void*)(uintptr_t)gptr,
      (__attribute__((address_space(3))) void*)(uintptr_t)lptr, 16, 0, 0);
}

__device__ __forceinline__ float sigm(float x) { return 1.f / (1.f + __expf(-x)); }
__device__ __forceinline__ float tanh_f(float x) { return 2.f / (1.f + __expf(-2.f * x)) - 1.f; }

// ---------------- pack / convert kernels ----------------

// x [B][S][I] f32 -> Xc bf16 [S*B][I] with row m = s*128 + b
__global__ __launch_bounds__(256) void convert_x(const float* __restrict__ x, u16* __restrict__ Xc) {
  int t = blockIdx.x * 256 + threadIdx.x;  // 0..4194303
  int i8 = t & 127;
  int s = (t >> 7) & 255;
  int b = t >> 15;
  const float4* src = (const float4*)(x + (((b << 8) + s) << 10) + (i8 << 3));
  float4 a = src[0], c = src[1];
  uint4 o;
  o.x = pack2bf(a.x, a.y); o.y = pack2bf(a.z, a.w);
  o.z = pack2bf(c.x, c.y); o.w = pack2bf(c.z, c.w);
  *(uint4*)(Xc + (((s << 7) + b) << 10) + (i8 << 3)) = o;
}

__global__ __launch_bounds__(256) void pack_w(const float* __restrict__ Wf, const float* __restrict__ Wi,
                                              const float* __restrict__ Wc, const float* __restrict__ Wo,
                                              u16* __restrict__ Whp, u16* __restrict__ Wxp) {
  int t = blockIdx.x * 256 + threadIdx.x;  // 0..524287
  int k8 = t & 127, n = t >> 7;
  int g = n >> 10, h = n & 1023;
  const float* W = (g == 0) ? Wf : (g == 1) ? Wi : (g == 2) ? Wc : Wo;
  const float4* ph = (const float4*)(W + h * 2048 + (k8 << 3));
  float4 a = ph[0], b = ph[1];
  uint4 oh;
  oh.x = pack2bf(a.x, a.y); oh.y = pack2bf(a.z, a.w);
  oh.z = pack2bf(b.x, b.y); oh.w = pack2bf(b.z, b.w);
  *(uint4*)(Whp + n * 1024 + (k8 << 3)) = oh;
  const float4* px = (const float4*)(W + h * 2048 + 1024 + (k8 << 3));
  float4 c = px[0], d = px[1];
  uint4 ox;
  ox.x = pack2bf(c.x, c.y); ox.y = pack2bf(c.z, c.w);
  ox.z = pack2bf(d.x, d.y); ox.w = pack2bf(d.z, d.w);
  *(uint4*)(Wxp + n * 1024 + (k8 << 3)) = ox;
}

__global__ __launch_bounds__(256) void pack_b(const float* __restrict__ bf_, const float* __restrict__ bi,
                                              const float* __restrict__ bc, const float* __restrict__ bo,
                                              float* __restrict__ biasp) {
  if (blockIdx.x == 0 && threadIdx.x < 128) g_bars[threadIdx.x] = 0;  // reset sync each replay
  int n = blockIdx.x * 256 + threadIdx.x;  // 0..4095
  int g = n >> 10, h = n & 1023;
  const float* b = (g == 0) ? bf_ : (g == 1) ? bi : (g == 2) ? bc : bo;
  biasp[n] = b[h];
}

// ---------------- phase 1 GEMM: gx = Xc @ Wxp^T + bias ----------------
// 128x128 tile, BK=64, single LDS buffer, 2 barriers/iter (m97 structure),
// XOR swizzle (c8 ^ (row&7)) for conflict-free ds_read_b128 frag loads.
__global__ __launch_bounds__(256) void gemm_x(const u16* __restrict__ A,   // Xc [32768][1024]
                                              const u16* __restrict__ Bw,  // Wxp [4096][1024]
                                              const float* __restrict__ bias,
                                              u16* __restrict__ gx,  // [2048][4096] chunk-local
                                              int m_base) {
  __shared__ __align__(16) u16 lds_a[128 * 64];
  __shared__ __align__(16) u16 lds_b[128 * 64];
  const int tid = threadIdx.x;
  const int lane = tid & 63, q = lane >> 4, cl = lane & 15;
  const int w = tid >> 6, wm = w & 1, wn = w >> 1;
  const int m0 = m_base + blockIdx.y * 128;
  const int n0 = blockIdx.x * 128;
  f32x4 acc[4][4] = {};

  for (int it = 0; it < 16; ++it) {
    const int k0 = it * 64;
#pragma unroll
    for (int itn = 0; itn < 4; ++itn) {  // A: 1024 chunks of 16B
      int j = itn * 256 + tid;
      int row = j >> 3, c8s = (j & 7) ^ (row & 7);
      gl2lds16(A + (m0 + row) * 1024 + k0 + c8s * 8, &lds_a[j * 8]);
    }
#pragma unroll
    for (int itn = 0; itn < 4; ++itn) {  // B: 1024 chunks
      int j = itn * 256 + tid;
      int row = j >> 3, c8s = (j & 7) ^ (row & 7);
      gl2lds16(Bw + (n0 + row) * 1024 + k0 + c8s * 8, &lds_b[j * 8]);
    }
    asm volatile("s_waitcnt vmcnt(0)" ::: "memory");
    __syncthreads();
#pragma unroll
    for (int kk = 0; kk < 2; ++kk) {
      bf16x8 af[4], bfr[4];
#pragma unroll
      for (int mt = 0; mt < 4; ++mt) {
        int row = wm * 64 + mt * 16 + cl;
        int c8 = (kk * 4 + q) ^ (row & 7);
        af[mt] = *(const bf16x8*)&lds_a[row * 64 + c8 * 8];
      }
#pragma unroll
      for (int nt = 0; nt < 4; ++nt) {
        int row = wn * 64 + nt * 16 + cl;
        int c8 = (kk * 4 + q) ^ (row & 7);
        bfr[nt] = *(const bf16x8*)&lds_b[row * 64 + c8 * 8];
      }
#pragma unroll
      for (int mt = 0; mt < 4; ++mt)
#pragma unroll
        for (int nt = 0; nt < 4; ++nt)
          acc[mt][nt] = __builtin_amdgcn_mfma_f32_16x16x32_bf16(af[mt], bfr[nt], acc[mt][nt], 0, 0, 0);
    }
    __syncthreads();
  }
  // epilogue: C[m][n], m = wm*64+mt*16+q*4+r, n = wn*64+nt*16+cl
#pragma unroll
  for (int nt = 0; nt < 4; ++nt) {
    int n = n0 + wn * 64 + nt * 16 + cl;
    float bv = bias[n];
#pragma unroll
    for (int mt = 0; mt < 4; ++mt) {
#pragma unroll
      for (int r = 0; r < 4; ++r) {
        int m_loc = blockIdx.y * 128 + wm * 64 + mt * 16 + q * 4 + r;
        gx[m_loc * 4096 + n] = f2bf(acc[mt][nt][r] + bv);
      }
    }
  }
}

// ---------------- phase 2: persistent recurrent kernel (16 steps / launch) ----------------
// Block bx: hgrp = bx&63 (h0 = 16*hgrp), mq = bx>>6 (m0 = 32*mq batch rows).
// 8 waves: wn = w&1 (32 of 64 Wh rows), kh = w>>1 (K-quarter). breg[16] = Wh slice in VGPRs.
// Ring slot layout: [hgrp][m(128)][hl(16)] bf16 -> element (m,h) at (h>>4)*2048 + m*16 + (h&15).
__global__ __launch_bounds__(512, 2) void lstm_chunk(const u16* __restrict__ Whp,   // [4096][1024]
                                                     const u16* __restrict__ gx,    // [2048][4096]
                                                     u16* __restrict__ hring,       // 32 slots
                                                     float* __restrict__ cws,       // [128][1024]
                                                     float* __restrict__ out,       // [128][256][1024]
                                                     int s_base) {
  __shared__ __align__(16) u16 lds_a[2][4][32][128];  // [buf][kh][row][k-elems] = 64 KB
  __shared__ float pre[4][64][34];                    // [kh][n_loc][m] (pad 34)

  const int tid = threadIdx.x;
  const int lane = tid & 63;
  const int w = tid >> 6;   // 0..7
  const int wn = w & 1;
  const int kh = w >> 1;
  const int l5 = lane >> 5;
  const int r31 = lane & 31;
  const int hgrp = blockIdx.x & 63, mq = blockIdx.x >> 6;
  const int h0 = hgrp * 16, m0 = mq * 32;
  unsigned* ctr = &g_bars[mq * 32];

  // persistent B fragments (loaded once per launch): 16 x bf16x8 = 64 VGPR
  bf16x8 breg[16];
  {
    const int n_loc = wn * 32 + r31;                       // 0..63: g*16 + hl
    const int ng = ((n_loc >> 4) << 10) + h0 + (n_loc & 15);
    const u16* wp = Whp + ng * 1024 + kh * 256 + l5 * 8;
#pragma unroll
    for (int ks = 0; ks < 16; ++ks) breg[ks] = *(const bf16x8*)(wp + ks * 16);
  }

  // cell ownership: thread -> (m=tid>>4, h=tid&15); c-state stays in a register
  const int cm = tid >> 4, chl = tid & 15;
  const int mg = m0 + cm, hg = h0 + chl;
  float creg = cws[mg * 1024 + hg];

  for (int t = 0; t < 16; ++t) {
    const int s = s_base + t;
    const u16* hin = hring + (s & 31) * 131072;
    u16* hout = hring + ((s + 1) & 31) * 131072;

    // gx prefetch (independent of the recurrence) -- issue BEFORE the poll
    const int grow = ((s & 15) << 7) + mg;
    const u16 gxv0 = gx[grow * 4096 + hg];
    const u16 gxv1 = gx[grow * 4096 + 1024 + hg];
    const u16 gxv2 = gx[grow * 4096 + 2048 + hg];
    const u16 gxv3 = gx[grow * 4096 + 3072 + hg];

    // wait for all 64 blocks of this batch-quarter to have published step s-1's h
    if (tid == 0) {
      const unsigned tgt = 64u * (unsigned)s;
      while (__hip_atomic_load(ctr, __ATOMIC_RELAXED, __HIP_MEMORY_SCOPE_AGENT) < tgt)
        __builtin_amdgcn_s_sleep(1);
    }
    __syncthreads();

    // stage half 0 (k-cols [khs*256, +128)); 16B granule swizzle u^(row&15)
#pragma unroll
    for (int it = 0; it < 4; ++it) {
      const int j = it * 512 + tid;  // 0..2047 granules
      const int khs = j >> 9, row = (j >> 4) & 31, u = j & 15;
      const int col8 = (khs << 5) + (u ^ (row & 15));  // 8-col granule index
      gl2lds16(hin + ((col8 >> 1) << 11) + ((m0 + row) << 4) + ((col8 & 1) << 3),
               (u16*)lds_a + j * 8);
    }
    asm volatile("s_waitcnt vmcnt(0)" ::: "memory");
    __syncthreads();
    // stage half 1 into buf 1 (async; overlaps buf-0 MFMAs)
#pragma unroll
    for (int it = 0; it < 4; ++it) {
      const int j = it * 512 + tid;
      const int khs = j >> 9, row = (j >> 4) & 31, u = j & 15;
      const int col8 = (khs << 5) + 16 + (u ^ (row & 15));
      gl2lds16(hin + ((col8 >> 1) << 11) + ((m0 + row) << 4) + ((col8 & 1) << 3),
               (u16*)lds_a + 16384 + j * 8);
    }

    f32x16 acc0 = {}, acc1 = {};  // two chains (even/odd kstep) to cover MFMA latency
#pragma unroll
    for (int ksl = 0; ksl < 8; ++ksl) {
      const int u = ((ksl << 1) + l5) ^ (r31 & 15);
      const bf16x8 av = *(const bf16x8*)&lds_a[0][kh][r31][u << 3];
      if (ksl & 1)
        acc1 = __builtin_amdgcn_mfma_f32_32x32x16_bf16(av, breg[ksl], acc1, 0, 0, 0);
      else
        acc0 = __builtin_amdgcn_mfma_f32_32x32x16_bf16(av, breg[ksl], acc0, 0, 0, 0);
    }
    asm volatile("s_waitcnt vmcnt(0)" ::: "memory");
    __syncthreads();
#pragma unroll
    for (int ksl = 0; ksl < 8; ++ksl) {
      const int u = ((ksl << 1) + l5) ^ (r31 & 15);
      const bf16x8 av = *(const bf16x8*)&lds_a[1][kh][r31][u << 3];
      if (ksl & 1)
        acc1 = __builtin_amdgcn_mfma_f32_32x32x16_bf16(av, breg[8 + ksl], acc1, 0, 0, 0);
      else
        acc0 = __builtin_amdgcn_mfma_f32_32x32x16_bf16(av, breg[8 + ksl], acc0, 0, 0, 0);
    }

    // K-partial to LDS: C col = lane&31 (n), row = (r&3)+8*(r>>2)+4*(lane>>5) (m)
#pragma unroll
    for (int r = 0; r < 16; ++r) {
      const int m_l = (r & 3) + ((r >> 2) << 3) + (l5 << 2);
      pre[kh][wn * 32 + r31][m_l] = acc0[r] + acc1[r];
    }
    __syncthreads();

    // fused cell update: sum 4 K-partials + gates_x, activations, write h/out
    float p0 = pre[0][chl][cm] + pre[1][chl][cm] + pre[2][chl][cm] + pre[3][chl][cm] + bf2f(gxv0);
    float p1 = pre[0][16 + chl][cm] + pre[1][16 + chl][cm] + pre[2][16 + chl][cm] + pre[3][16 + chl][cm] + bf2f(gxv1);
    float p2 = pre[0][32 + chl][cm] + pre[1][32 + chl][cm] + pre[2][32 + chl][cm] + pre[3][32 + chl][cm] + bf2f(gxv2);
    float p3 = pre[0][48 + chl][cm] + pre[1][48 + chl][cm] + pre[2][48 + chl][cm] + pre[3][48 + chl][cm] + bf2f(gxv3);
    const float fg = sigm(p0), ig = sigm(p1), gg = tanh_f(p2), og = sigm(p3);
    creg = creg * fg + ig * gg;
    const float hn = tanh_f(creg) * og;
    // coherent (agent-scope, write-through) h store; block owns whole 128B lines
    __hip_atomic_store(&hout[hgrp * 2048 + mg * 16 + chl], f2bf(hn),
                       __ATOMIC_RELAXED, __HIP_MEMORY_SCOPE_AGENT);
    out[(mg * 256 + s) * 1024 + hg] = hn;

    // arrival: own stores complete (per-wave vmcnt) -> block barrier -> counter bump
    asm volatile("s_waitcnt vmcnt(0)" ::: "memory");
    __syncthreads();
    if (tid == 0)
      __hip_atomic_fetch_add(ctr, 1u, __ATOMIC_RELAXED, __HIP_MEMORY_SCOPE_AGENT);
  }
  cws[mg * 1024 + hg] = creg;
}

// ---------------- launch ----------------

extern "C" void kernel_launch(void* const* d_in, const int* in_sizes, int n_in,
                              void* d_out, int out_size, void* d_ws, size_t ws_size,
                              hipStream_t stream) {
  const float* x   = (const float*)d_in[0];
  const float* Wf  = (const float*)d_in[1];
  const float* bf_ = (const float*)d_in[2];
  const float* Wi  = (const float*)d_in[3];
  const float* bi  = (const float*)d_in[4];
  const float* Wc  = (const float*)d_in[5];
  const float* bc  = (const float*)d_in[6];
  const float* Wo  = (const float*)d_in[7];
  const float* bo  = (const float*)d_in[8];
  float* out = (float*)d_out;
  char* ws = (char*)d_ws;

  const size_t NEEDED = 109592576;
  if (ws_size < NEEDED) return;  // fail cleanly (wrong output) instead of faulting

  u16*  Xc    = (u16*)(ws);
  u16*  Whp   = (u16*)(ws + 67108864);
  u16*  Wxp   = (u16*)(ws + 75497472);
  float* biasp = (float*)(ws + 83886080);
  u16*  hring = (u16*)(ws + 83902464);   // 32 x 262144 B
  float* cws  = (float*)(ws + 92291072);
  u16*  gx    = (u16*)(ws + 92815360);

  // zero h ring slot 0 + c
  hipMemsetAsync(ws + 83902464, 0, 262144, stream);
  hipMemsetAsync(ws + 92291072, 0, 524288, stream);
  convert_x<<<16384, 256, 0, stream>>>(x, Xc);
  pack_w<<<2048, 256, 0, stream>>>(Wf, Wi, Wc, Wo, Whp, Wxp);
  pack_b<<<16, 256, 0, stream>>>(bf_, bi, bc, bo, biasp);  // also zeroes g_bars

  for (int c = 0; c < 16; ++c) {
    gemm_x<<<dim3(32, 16), 256, 0, stream>>>(Xc, Wxp, biasp, gx, c * 2048);
    int sbase = c * 16;
    void* args[6];
    args[0] = (void*)&Whp;
    args[1] = (void*)&gx;
    args[2] = (void*)&hring;
    args[3] = (void*)&cws;
    args[4] = (void*)&out;
    args[5] = (void*)&sbase;
    if (hipLaunchCooperativeKernel((const void*)lstm_chunk, dim3(256), dim3(512),
                                   args, 0, stream) != hipSuccess) {
      // fallback: plain launch. 256 blocks, 1/CU (LDS-limited) => co-resident;
      // the per-mq counter sync does not require more.
      lstm_chunk<<<dim3(256), dim3(512), 0, stream>>>(Whp, gx, hring, cws, out, sbase);
    }
  }
}

// Round 3
// 1581.959 us; speedup vs baseline: 4.6374x; 1.3594x over previous
//
#include <hip/hip_runtime.h>
#include <stdint.h>

// LSTM  B=128, S=256, I=1024, H=1024
// ONE fused persistent kernel (coop, 256 blocks x 512 thr, 1 block/CU):
//   blocks 128..255: x-GEMM producer  gx = Xc @ Wxp^T + bias  (full [32768][4096] bf16),
//     s-major tile order, sc1 stores, bump gxrdy[s] (32 tiles per s).
//   blocks 0..127:  recurrence consumer, block = (32 h x 4 gates) x (32 batch rows),
//     Wh slice pinned in VGPRs (breg[32] = 128 VGPR), h exchanged through a
//     257-slot ring (one slot per step: every line written once/read once per
//     launch -> plain cached reads can never be stale), per-mq relaxed counters.
//
// Workspace layout (bytes)  [ws observed = 512 MiB via harness poison fills]:
//   Xc    bf16 [S*B][I]        67,108,864  @ 0           (row m = s*128 + b)
//   Whp   bf16 [4H][H]          8,388,608  @ 67,108,864  (n = gate*1024 + h; f,i,g,o)
//   Wxp   bf16 [4H][I]          8,388,608  @ 75,497,472
//   biasp f32  [4H]                16,384  @ 83,886,080
//   cws   f32  [128][1024]        524,288  @ 83,902,464
//   hring bf16 257*[32][128][32] 67,371,008 @ 84,426,752 (slot s = h entering step s)
//   gx    bf16 [32768][4096]  268,435,456  @ 151,797,760
// total 420,233,216

typedef unsigned short u16;
typedef unsigned int u32;
typedef __bf16 bf16x8 __attribute__((ext_vector_type(8)));
typedef float f32x4 __attribute__((ext_vector_type(4)));
typedef float f32x16 __attribute__((ext_vector_type(16)));

__device__ unsigned g_bars[128];   // per-mq h counters at g_bars[mq*32]
__device__ unsigned g_gxrdy[256];  // per-step gx tile counters (target 32)

__device__ __forceinline__ u16 f2bf(float f) {
  u32 u = __builtin_bit_cast(u32, f);
  u = (u + 0x7fffu + ((u >> 16) & 1u)) >> 16;
  return (u16)u;
}
__device__ __forceinline__ float bf2f(u16 s) {
  u32 u = ((u32)s) << 16;
  return __builtin_bit_cast(float, u);
}
__device__ __forceinline__ u32 pack2bf(float a, float b) {
  return (u32)f2bf(a) | ((u32)f2bf(b) << 16);
}

// async global -> LDS, 16B per lane. LDS dest must be wave-uniform base + lane*16.
__device__ __forceinline__ void gl2lds16(const void* gptr, void* lptr) {
  __builtin_amdgcn_global_load_lds(
      (__attribute__((address_space(1))) void*)(uintptr_t)gptr,
      (__attribute__((address_space(3))) void*)(uintptr_t)lptr, 16, 0, 0);
}

__device__ __forceinline__ float sigm(float x) { return 1.f / (1.f + __expf(-x)); }
__device__ __forceinline__ float tanh_f(float x) { return 2.f / (1.f + __expf(-2.f * x)) - 1.f; }

// ---------------- pack / convert kernels ----------------

// x [B][S][I] f32 -> Xc bf16 [S*B][I] with row m = s*128 + b
__global__ __launch_bounds__(256) void convert_x(const float* __restrict__ x, u16* __restrict__ Xc) {
  int t = blockIdx.x * 256 + threadIdx.x;  // 0..4194303
  int i8 = t & 127;
  int s = (t >> 7) & 255;
  int b = t >> 15;
  const float4* src = (const float4*)(x + (((b << 8) + s) << 10) + (i8 << 3));
  float4 a = src[0], c = src[1];
  uint4 o;
  o.x = pack2bf(a.x, a.y); o.y = pack2bf(a.z, a.w);
  o.z = pack2bf(c.x, c.y); o.w = pack2bf(c.z, c.w);
  *(uint4*)(Xc + (((s << 7) + b) << 10) + (i8 << 3)) = o;
}

__global__ __launch_bounds__(256) void pack_w(const float* __restrict__ Wf, const float* __restrict__ Wi,
                                              const float* __restrict__ Wc, const float* __restrict__ Wo,
                                              u16* __restrict__ Whp, u16* __restrict__ Wxp) {
  int t = blockIdx.x * 256 + threadIdx.x;  // 0..524287
  int k8 = t & 127, n = t >> 7;
  int g = n >> 10, h = n & 1023;
  const float* W = (g == 0) ? Wf : (g == 1) ? Wi : (g == 2) ? Wc : Wo;
  const float4* ph = (const float4*)(W + h * 2048 + (k8 << 3));
  float4 a = ph[0], b = ph[1];
  uint4 oh;
  oh.x = pack2bf(a.x, a.y); oh.y = pack2bf(a.z, a.w);
  oh.z = pack2bf(b.x, b.y); oh.w = pack2bf(b.z, b.w);
  *(uint4*)(Whp + n * 1024 + (k8 << 3)) = oh;
  const float4* px = (const float4*)(W + h * 2048 + 1024 + (k8 << 3));
  float4 c = px[0], d = px[1];
  uint4 ox;
  ox.x = pack2bf(c.x, c.y); ox.y = pack2bf(c.z, c.w);
  ox.z = pack2bf(d.x, d.y); ox.w = pack2bf(d.z, d.w);
  *(uint4*)(Wxp + n * 1024 + (k8 << 3)) = ox;
}

__global__ __launch_bounds__(256) void pack_b(const float* __restrict__ bf_, const float* __restrict__ bi,
                                              const float* __restrict__ bc, const float* __restrict__ bo,
                                              float* __restrict__ biasp) {
  if (blockIdx.x == 0 && threadIdx.x < 128) g_bars[threadIdx.x] = 0;   // reset sync each replay
  if (blockIdx.x == 1) g_gxrdy[threadIdx.x] = 0;                       // 256 threads
  int n = blockIdx.x * 256 + threadIdx.x;  // 0..4095
  int g = n >> 10, h = n & 1023;
  const float* b = (g == 0) ? bf_ : (g == 1) ? bi : (g == 2) ? bc : bo;
  biasp[n] = b[h];
}

// ---------------- fused persistent kernel ----------------
__global__ __launch_bounds__(512, 2) void lstm_fused(
    const u16* __restrict__ Whp,   // [4096][1024]
    const u16* __restrict__ Wxp,   // [4096][1024]
    const u16* __restrict__ Xc,    // [32768][1024]
    const float* __restrict__ biasp,
    u16* __restrict__ gx,          // [32768][4096]
    u16* __restrict__ hring,       // 257 slots x [32][128][32] bf16
    float* __restrict__ cws,       // [128][1024]
    float* __restrict__ out) {     // [128][256][1024] f32
  __shared__ __align__(16) unsigned char smem[100352];
  const int tid = threadIdx.x;
  const int bid = blockIdx.x;

  if (bid >= 128) {
    // ================= GEMM producer role =================
    u16* lds_a = (u16*)smem;            // [2][128*64] (2 x 16KB)
    u16* lds_b = (u16*)(smem + 32768);  // [2][128*64]
    const int gid = bid - 128;
    const int lane = tid & 63, q = lane >> 4, cl = lane & 15;
    const int w = tid >> 6, wm = w & 1, wn = w >> 1;  // wm 0..1 (64m), wn 0..3 (32n)
    const int n0 = (gid & 31) * 128;                  // fixed n-panel per block (L2-resident B)

    for (int t = 0; t < 64; ++t) {
      const int s = (gid + (t << 7)) >> 5;  // s-major tile order
      const int m0 = s << 7;
      f32x4 acc[4][2] = {};

      auto stage = [&](int buf, int it) {
        const int k0 = it * 64;
#pragma unroll
        for (int itn = 0; itn < 2; ++itn) {  // A: 1024 granules of 16B
          int j = itn * 512 + tid;
          int row = j >> 3, c8s = (j & 7) ^ (row & 7);
          gl2lds16(Xc + (m0 + row) * 1024 + k0 + c8s * 8, lds_a + buf * 8192 + j * 8);
        }
#pragma unroll
        for (int itn = 0; itn < 2; ++itn) {  // B: 1024 granules
          int j = itn * 512 + tid;
          int row = j >> 3, c8s = (j & 7) ^ (row & 7);
          gl2lds16(Wxp + (n0 + row) * 1024 + k0 + c8s * 8, lds_b + buf * 8192 + j * 8);
        }
      };

      stage(0, 0);
      for (int it = 0; it < 16; ++it) {
        const int buf = it & 1;
        asm volatile("s_waitcnt vmcnt(0)" ::: "memory");
        __syncthreads();
        if (it < 15) stage(buf ^ 1, it + 1);
#pragma unroll
        for (int kk = 0; kk < 2; ++kk) {
          bf16x8 af[4], bfr[2];
#pragma unroll
          for (int mt = 0; mt < 4; ++mt) {
            int row = wm * 64 + mt * 16 + cl;
            int c8 = (kk * 4 + q) ^ (row & 7);
            af[mt] = *(const bf16x8*)&lds_a[buf * 8192 + row * 64 + c8 * 8];
          }
#pragma unroll
          for (int nt = 0; nt < 2; ++nt) {
            int row = wn * 32 + nt * 16 + cl;
            int c8 = (kk * 4 + q) ^ (row & 7);
            bfr[nt] = *(const bf16x8*)&lds_b[buf * 8192 + row * 64 + c8 * 8];
          }
#pragma unroll
          for (int mt = 0; mt < 4; ++mt)
#pragma unroll
            for (int nt = 0; nt < 2; ++nt)
              acc[mt][nt] = __builtin_amdgcn_mfma_f32_16x16x32_bf16(af[mt], bfr[nt], acc[mt][nt], 0, 0, 0);
        }
      }
      // epilogue: bias + bf16, sc1 (write-through) stores so consumers see LLC data
#pragma unroll
      for (int nt = 0; nt < 2; ++nt) {
        int n = n0 + wn * 32 + nt * 16 + cl;
        float bv = biasp[n];
#pragma unroll
        for (int mt = 0; mt < 4; ++mt)
#pragma unroll
          for (int r = 0; r < 4; ++r) {
            int m = m0 + wm * 64 + mt * 16 + q * 4 + r;
            __hip_atomic_store(&gx[m * 4096 + n], f2bf(acc[mt][nt][r] + bv),
                               __ATOMIC_RELAXED, __HIP_MEMORY_SCOPE_AGENT);
          }
      }
      asm volatile("s_waitcnt vmcnt(0)" ::: "memory");
      __syncthreads();
      if (tid == 0)
        __hip_atomic_fetch_add(&g_gxrdy[s], 1u, __ATOMIC_RELAXED, __HIP_MEMORY_SCOPE_AGENT);
    }
    return;
  }

  // ================= recurrence consumer role =================
  // hgrp = bid&31 -> h0 = 32*hgrp (n-set = 4 gates x 32 h = 128 Whp rows),
  // mq = bid>>5 -> m0 = 32*mq. Waves: wn = w&3 (32 n-rows), kh = w>>2 (K half of 512).
  u16* lds_h = (u16*)smem;              // [32][1024] bf16 = 64KB (swizzled granules)
  float* pre = (float*)(smem + 65536);  // [2][128][34] f32 = 34816B

  const int lane = tid & 63;
  const int w = tid >> 6;
  const int wn = w & 3;
  const int kh = w >> 2;
  const int l5 = lane >> 5, r31 = lane & 31;
  const int hgrp = bid & 31, mq = bid >> 5;
  const int h0 = hgrp * 32, m0 = mq * 32;
  unsigned* ctr = &g_bars[mq * 32];

  // persistent Wh fragments: 32 x bf16x8 = 128 VGPR
  bf16x8 breg[32];
  {
    const int n_loc = wn * 32 + r31;  // 0..127 = gate*32 + h-in
    const int ng = ((n_loc >> 5) << 10) + h0 + (n_loc & 31);
    const u16* wp = Whp + ng * 1024 + kh * 512 + l5 * 8;
#pragma unroll
    for (int ks = 0; ks < 32; ++ks) breg[ks] = *(const bf16x8*)(wp + ks * 16);
  }

  // cell ownership: thread -> (m = tid>>4, h pair = (tid&15)*2); c-state in regs
  const int cm = tid >> 4, ch2 = (tid & 15) << 1;
  const int mg = m0 + cm;
  float2 cp = *(const float2*)&cws[mg * 1024 + h0 + ch2];
  float c0v = cp.x, c1v = cp.y;

  for (int s = 0; s < 256; ++s) {
    const u16* hin = hring + s * 131072;
    u16* hout = hring + (s + 1) * 131072;

    if (tid == 0) {
      while (__hip_atomic_load(&g_gxrdy[s], __ATOMIC_RELAXED, __HIP_MEMORY_SCOPE_AGENT) < 32u)
        __builtin_amdgcn_s_sleep(1);
      const unsigned tgt = 32u * (unsigned)s;
      while (__hip_atomic_load(ctr, __ATOMIC_RELAXED, __HIP_MEMORY_SCOPE_AGENT) < tgt)
        __builtin_amdgcn_s_sleep(1);
    }
    __syncthreads();

    // stage h tile [32 m][1024 k]: 4096 granules, LDS[row][u] <- src granule u^(row&15)
    // slot layout: elem (m,h) at (h>>5)*4096 + m*32 + (h&31)  (u16 units)
#pragma unroll
    for (int itn = 0; itn < 8; ++itn) {
      int j = itn * 512 + tid;
      int row = j >> 7, u = j & 127;
      int us = u ^ (row & 15);
      gl2lds16(hin + ((us >> 2) << 12) + ((m0 + row) << 5) + ((us & 3) << 3),
               lds_h + j * 8);
    }
    // gx loads (gated by gxrdy poll) -- issue now, consumed after MFMA
    const int gbase = (s * 128 + mg) * 4096 + h0 + ch2;
    const u32 gq0 = *(const u32*)(gx + gbase);
    const u32 gq1 = *(const u32*)(gx + gbase + 1024);
    const u32 gq2 = *(const u32*)(gx + gbase + 2048);
    const u32 gq3 = *(const u32*)(gx + gbase + 3072);
    asm volatile("s_waitcnt vmcnt(0)" ::: "memory");
    __syncthreads();

    f32x16 acc0 = {}, acc1 = {};  // two chains cover MFMA latency
#pragma unroll
    for (int ks = 0; ks < 32; ++ks) {
      const int g = kh * 64 + ks * 2 + l5;
      const bf16x8 av = *(const bf16x8*)&lds_h[r31 * 1024 + ((g ^ (r31 & 15)) << 3)];
      if (ks & 1)
        acc1 = __builtin_amdgcn_mfma_f32_32x32x16_bf16(av, breg[ks], acc1, 0, 0, 0);
      else
        acc0 = __builtin_amdgcn_mfma_f32_32x32x16_bf16(av, breg[ks], acc0, 0, 0, 0);
    }

    // K-partial to LDS: C col = lane&31 (n), row m = (r&3)+8*(r>>2)+4*(lane>>5)
#pragma unroll
    for (int r = 0; r < 16; ++r) {
      const int m_l = (r & 3) + ((r >> 2) << 3) + (l5 << 2);
      pre[(kh * 128 + wn * 32 + r31) * 34 + m_l] = acc0[r] + acc1[r];
    }
    __syncthreads();

    // fused cell update: 2 cells per thread (h pair)
    float p0[4], p1[4];
#pragma unroll
    for (int gi = 0; gi < 4; ++gi) {
      const int n0l = gi * 32 + ch2;
      p0[gi] = pre[n0l * 34 + cm] + pre[(128 + n0l) * 34 + cm];
      p1[gi] = pre[(n0l + 1) * 34 + cm] + pre[(128 + n0l + 1) * 34 + cm];
    }
    p0[0] += bf2f((u16)(gq0 & 0xffff)); p1[0] += bf2f((u16)(gq0 >> 16));
    p0[1] += bf2f((u16)(gq1 & 0xffff)); p1[1] += bf2f((u16)(gq1 >> 16));
    p0[2] += bf2f((u16)(gq2 & 0xffff)); p1[2] += bf2f((u16)(gq2 >> 16));
    p0[3] += bf2f((u16)(gq3 & 0xffff)); p1[3] += bf2f((u16)(gq3 >> 16));
    const float fg0 = sigm(p0[0]), ig0 = sigm(p0[1]), gg0 = tanh_f(p0[2]), og0 = sigm(p0[3]);
    const float fg1 = sigm(p1[0]), ig1 = sigm(p1[1]), gg1 = tanh_f(p1[2]), og1 = sigm(p1[3]);
    c0v = c0v * fg0 + ig0 * gg0;
    c1v = c1v * fg1 + ig1 * gg1;
    const float hn0 = tanh_f(c0v) * og0;
    const float hn1 = tanh_f(c1v) * og1;

    // coherent h store (one u32 = 2 bf16; block owns whole 64B runs per m)
    __hip_atomic_store((u32*)(hout + hgrp * 4096 + mg * 32 + ch2), pack2bf(hn0, hn1),
                       __ATOMIC_RELAXED, __HIP_MEMORY_SCOPE_AGENT);
    *(float2*)&out[(mg * 256 + s) * 1024 + h0 + ch2] = make_float2(hn0, hn1);

    asm volatile("s_waitcnt vmcnt(0)" ::: "memory");
    __syncthreads();
    if (tid == 0)
      __hip_atomic_fetch_add(ctr, 1u, __ATOMIC_RELAXED, __HIP_MEMORY_SCOPE_AGENT);
  }
  *(float2*)&cws[mg * 1024 + h0 + ch2] = make_float2(c0v, c1v);
}

// ---------------- launch ----------------

extern "C" void kernel_launch(void* const* d_in, const int* in_sizes, int n_in,
                              void* d_out, int out_size, void* d_ws, size_t ws_size,
                              hipStream_t stream) {
  const float* x   = (const float*)d_in[0];
  const float* Wf  = (const float*)d_in[1];
  const float* bf_ = (const float*)d_in[2];
  const float* Wi  = (const float*)d_in[3];
  const float* bi  = (const float*)d_in[4];
  const float* Wc  = (const float*)d_in[5];
  const float* bc  = (const float*)d_in[6];
  const float* Wo  = (const float*)d_in[7];
  const float* bo  = (const float*)d_in[8];
  float* out = (float*)d_out;
  char* ws = (char*)d_ws;

  const size_t NEEDED = 420233216;
  if (ws_size < NEEDED) return;  // fail cleanly (wrong output) instead of faulting

  u16*  Xc    = (u16*)(ws);
  u16*  Whp   = (u16*)(ws + 67108864);
  u16*  Wxp   = (u16*)(ws + 75497472);
  float* biasp = (float*)(ws + 83886080);
  float* cws  = (float*)(ws + 83902464);
  u16*  hring = (u16*)(ws + 84426752);    // 257 x 262144 B
  u16*  gx    = (u16*)(ws + 151797760);   // 256 MB

  hipMemsetAsync(ws + 83902464, 0, 524288, stream);  // cws = 0
  hipMemsetAsync(ws + 84426752, 0, 262144, stream);  // hring slot 0 = 0
  convert_x<<<16384, 256, 0, stream>>>(x, Xc);
  pack_w<<<2048, 256, 0, stream>>>(Wf, Wi, Wc, Wo, Whp, Wxp);
  pack_b<<<16, 256, 0, stream>>>(bf_, bi, bc, bo, biasp);  // also zeroes g_bars/g_gxrdy

  void* args[8];
  args[0] = (void*)&Whp;
  args[1] = (void*)&Wxp;
  args[2] = (void*)&Xc;
  args[3] = (void*)&biasp;
  args[4] = (void*)&gx;
  args[5] = (void*)&hring;
  args[6] = (void*)&cws;
  args[7] = (void*)&out;
  if (hipLaunchCooperativeKernel((const void*)lstm_fused, dim3(256), dim3(512),
                                 args, 0, stream) != hipSuccess) {
    // fallback: plain launch. 256 blocks, 1/CU (LDS-limited) => co-resident;
    // flag-based sync does not require more than co-residency.
    lstm_fused<<<dim3(256), dim3(512), 0, stream>>>(Whp, Wxp, Xc, biasp, gx, hring, cws, out);
  }
}

// Round 4
// 1575.619 us; speedup vs baseline: 4.6561x; 1.0040x over previous
//
#include <hip/hip_runtime.h>
#include <stdint.h>

// LSTM  B=128, S=256, I=1024, H=1024
// ONE fused persistent kernel (coop, 256 blocks x 512 thr, 1 block/CU):
//   blocks 128..255: x-GEMM producer  gx = Xc @ Wxp^T + bias  (full [32768][4096] bf16),
//     s-major tile order, sc1 stores, bump gxrdy[s] (32 tiles per s).
//   blocks 0..127:  recurrence consumer, block = (32 h x 4 gates) x (32 batch rows).
//     8 waves = (kh 0..3: K-quarter 256) x (wn 0..1: n-half 64). Wh slice pinned in
//     VGPRs (breg[32] = 128 VGPR). h is NOT staged in LDS: each wave streams its
//     A-fragments directly global->VGPR (16 frags x 16B/lane, 8 in flight) from the
//     257-slot h ring; K-partials exchanged via pre[4][128][33] (stride 33 = no bank
//     conflicts). 3 barriers/step. Per-mq relaxed counters; h stores sc1 (LLC).
//
// Workspace layout (bytes)  [ws observed = 512 MiB via harness poison fills]:
//   Xc    bf16 [S*B][I]        67,108,864  @ 0           (row m = s*128 + b)
//   Whp   bf16 [4H][H]          8,388,608  @ 67,108,864  (n = gate*1024 + h; f,i,g,o)
//   Wxp   bf16 [4H][I]          8,388,608  @ 75,497,472
//   biasp f32  [4H]                16,384  @ 83,886,080
//   cws   f32  [128][1024]        524,288  @ 83,902,464
//   hring bf16 257*[32][128][32] 67,371,008 @ 84,426,752 (slot s = h entering step s)
//   gx    bf16 [32768][4096]  268,435,456  @ 151,797,760
// total 420,233,216

typedef unsigned short u16;
typedef unsigned int u32;
typedef __bf16 bf16x8 __attribute__((ext_vector_type(8)));
typedef float f32x4 __attribute__((ext_vector_type(4)));
typedef float f32x16 __attribute__((ext_vector_type(16)));

__device__ unsigned g_bars[128];   // per-mq h counters at g_bars[mq*32]
__device__ unsigned g_gxrdy[256];  // per-step gx tile counters (target 32)

__device__ __forceinline__ u16 f2bf(float f) {
  u32 u = __builtin_bit_cast(u32, f);
  u = (u + 0x7fffu + ((u >> 16) & 1u)) >> 16;
  return (u16)u;
}
__device__ __forceinline__ float bf2f(u16 s) {
  u32 u = ((u32)s) << 16;
  return __builtin_bit_cast(float, u);
}
__device__ __forceinline__ u32 pack2bf(float a, float b) {
  return (u32)f2bf(a) | ((u32)f2bf(b) << 16);
}

// async global -> LDS, 16B per lane. LDS dest must be wave-uniform base + lane*16.
__device__ __forceinline__ void gl2lds16(const void* gptr, void* lptr) {
  __builtin_amdgcn_global_load_lds(
      (__attribute__((address_space(1))) void*)(uintptr_t)gptr,
      (__attribute__((address_space(3))) void*)(uintptr_t)lptr, 16, 0, 0);
}

__device__ __forceinline__ float sigm(float x) { return 1.f / (1.f + __expf(-x)); }
__device__ __forceinline__ float tanh_f(float x) { return 2.f / (1.f + __expf(-2.f * x)) - 1.f; }

// ---------------- pack / convert kernels ----------------

// x [B][S][I] f32 -> Xc bf16 [S*B][I] with row m = s*128 + b
__global__ __launch_bounds__(256) void convert_x(const float* __restrict__ x, u16* __restrict__ Xc) {
  int t = blockIdx.x * 256 + threadIdx.x;  // 0..4194303
  int i8 = t & 127;
  int s = (t >> 7) & 255;
  int b = t >> 15;
  const float4* src = (const float4*)(x + (((b << 8) + s) << 10) + (i8 << 3));
  float4 a = src[0], c = src[1];
  uint4 o;
  o.x = pack2bf(a.x, a.y); o.y = pack2bf(a.z, a.w);
  o.z = pack2bf(c.x, c.y); o.w = pack2bf(c.z, c.w);
  *(uint4*)(Xc + (((s << 7) + b) << 10) + (i8 << 3)) = o;
}

__global__ __launch_bounds__(256) void pack_w(const float* __restrict__ Wf, const float* __restrict__ Wi,
                                              const float* __restrict__ Wc, const float* __restrict__ Wo,
                                              u16* __restrict__ Whp, u16* __restrict__ Wxp) {
  int t = blockIdx.x * 256 + threadIdx.x;  // 0..524287
  int k8 = t & 127, n = t >> 7;
  int g = n >> 10, h = n & 1023;
  const float* W = (g == 0) ? Wf : (g == 1) ? Wi : (g == 2) ? Wc : Wo;
  const float4* ph = (const float4*)(W + h * 2048 + (k8 << 3));
  float4 a = ph[0], b = ph[1];
  uint4 oh;
  oh.x = pack2bf(a.x, a.y); oh.y = pack2bf(a.z, a.w);
  oh.z = pack2bf(b.x, b.y); oh.w = pack2bf(b.z, b.w);
  *(uint4*)(Whp + n * 1024 + (k8 << 3)) = oh;
  const float4* px = (const float4*)(W + h * 2048 + 1024 + (k8 << 3));
  float4 c = px[0], d = px[1];
  uint4 ox;
  ox.x = pack2bf(c.x, c.y); ox.y = pack2bf(c.z, c.w);
  ox.z = pack2bf(d.x, d.y); ox.w = pack2bf(d.z, d.w);
  *(uint4*)(Wxp + n * 1024 + (k8 << 3)) = ox;
}

__global__ __launch_bounds__(256) void pack_b(const float* __restrict__ bf_, const float* __restrict__ bi,
                                              const float* __restrict__ bc, const float* __restrict__ bo,
                                              float* __restrict__ biasp) {
  if (blockIdx.x == 0 && threadIdx.x < 128) g_bars[threadIdx.x] = 0;   // reset sync each replay
  if (blockIdx.x == 1) g_gxrdy[threadIdx.x] = 0;                       // 256 threads
  int n = blockIdx.x * 256 + threadIdx.x;  // 0..4095
  int g = n >> 10, h = n & 1023;
  const float* b = (g == 0) ? bf_ : (g == 1) ? bi : (g == 2) ? bc : bo;
  biasp[n] = b[h];
}

// ---------------- fused persistent kernel ----------------
__global__ __launch_bounds__(512, 2) void lstm_fused(
    const u16* __restrict__ Whp,   // [4096][1024]
    const u16* __restrict__ Wxp,   // [4096][1024]
    const u16* __restrict__ Xc,    // [32768][1024]
    const float* __restrict__ biasp,
    u16* __restrict__ gx,          // [32768][4096]
    u16* __restrict__ hring,       // 257 slots x [32][128][32] bf16
    float* __restrict__ cws,       // [128][1024]
    float* __restrict__ out) {     // [128][256][1024] f32
  __shared__ __align__(16) unsigned char smem[67584];
  const int tid = threadIdx.x;
  const int bid = blockIdx.x;

  if (bid >= 128) {
    // ================= GEMM producer role =================
    u16* lds_a = (u16*)smem;            // [2][128*64] (2 x 16KB)
    u16* lds_b = (u16*)(smem + 32768);  // [2][128*64]
    const int gid = bid - 128;
    const int lane = tid & 63, q = lane >> 4, cl = lane & 15;
    const int w = tid >> 6, wm = w & 1, wn = w >> 1;  // wm 0..1 (64m), wn 0..3 (32n)
    const int n0 = (gid & 31) * 128;                  // fixed n-panel per block (L2-resident B)

    for (int t = 0; t < 64; ++t) {
      const int s = (gid + (t << 7)) >> 5;  // s-major tile order
      const int m0 = s << 7;
      f32x4 acc[4][2] = {};

      auto stage = [&](int buf, int it) {
        const int k0 = it * 64;
#pragma unroll
        for (int itn = 0; itn < 2; ++itn) {  // A: 1024 granules of 16B
          int j = itn * 512 + tid;
          int row = j >> 3, c8s = (j & 7) ^ (row & 7);
          gl2lds16(Xc + (m0 + row) * 1024 + k0 + c8s * 8, lds_a + buf * 8192 + j * 8);
        }
#pragma unroll
        for (int itn = 0; itn < 2; ++itn) {  // B: 1024 granules
          int j = itn * 512 + tid;
          int row = j >> 3, c8s = (j & 7) ^ (row & 7);
          gl2lds16(Wxp + (n0 + row) * 1024 + k0 + c8s * 8, lds_b + buf * 8192 + j * 8);
        }
      };

      stage(0, 0);
      for (int it = 0; it < 16; ++it) {
        const int buf = it & 1;
        asm volatile("s_waitcnt vmcnt(0)" ::: "memory");
        __syncthreads();
        if (it < 15) stage(buf ^ 1, it + 1);
#pragma unroll
        for (int kk = 0; kk < 2; ++kk) {
          bf16x8 af[4], bfr[2];
#pragma unroll
          for (int mt = 0; mt < 4; ++mt) {
            int row = wm * 64 + mt * 16 + cl;
            int c8 = (kk * 4 + q) ^ (row & 7);
            af[mt] = *(const bf16x8*)&lds_a[buf * 8192 + row * 64 + c8 * 8];
          }
#pragma unroll
          for (int nt = 0; nt < 2; ++nt) {
            int row = wn * 32 + nt * 16 + cl;
            int c8 = (kk * 4 + q) ^ (row & 7);
            bfr[nt] = *(const bf16x8*)&lds_b[buf * 8192 + row * 64 + c8 * 8];
          }
#pragma unroll
          for (int mt = 0; mt < 4; ++mt)
#pragma unroll
            for (int nt = 0; nt < 2; ++nt)
              acc[mt][nt] = __builtin_amdgcn_mfma_f32_16x16x32_bf16(af[mt], bfr[nt], acc[mt][nt], 0, 0, 0);
        }
      }
      // epilogue: bias + bf16, sc1 (write-through) stores so consumers see LLC data
#pragma unroll
      for (int nt = 0; nt < 2; ++nt) {
        int n = n0 + wn * 32 + nt * 16 + cl;
        float bv = biasp[n];
#pragma unroll
        for (int mt = 0; mt < 4; ++mt)
#pragma unroll
          for (int r = 0; r < 4; ++r) {
            int m = m0 + wm * 64 + mt * 16 + q * 4 + r;
            __hip_atomic_store(&gx[m * 4096 + n], f2bf(acc[mt][nt][r] + bv),
                               __ATOMIC_RELAXED, __HIP_MEMORY_SCOPE_AGENT);
          }
      }
      asm volatile("s_waitcnt vmcnt(0)" ::: "memory");
      __syncthreads();
      if (tid == 0)
        __hip_atomic_fetch_add(&g_gxrdy[s], 1u, __ATOMIC_RELAXED, __HIP_MEMORY_SCOPE_AGENT);
    }
    return;
  }

  // ================= recurrence consumer role =================
  // hgrp = bid&31 -> h0 = 32*hgrp (n-set = 4 gates x 32 h = 128 Whp rows),
  // mq = bid>>5 -> m0 = 32*mq. Waves: kh = w>>1 (K-quarter 256), wn = w&1 (n-half 64).
  float* pre = (float*)smem;  // [4][128][33] f32 = 67584 B

  const int lane = tid & 63;
  const int w = tid >> 6;
  const int wn = w & 1;
  const int kh = w >> 1;
  const int l5 = lane >> 5, r31 = lane & 31;
  const int hgrp = bid & 31, mq = bid >> 5;
  const int h0 = hgrp * 32, m0 = mq * 32;
  unsigned* ctr = &g_bars[mq * 32];

  // persistent Wh fragments: breg[ks*2+nb], 32 x bf16x8 = 128 VGPR
  bf16x8 breg[32];
  {
#pragma unroll
    for (int nb = 0; nb < 2; ++nb) {
      const int n_loc = wn * 64 + nb * 32 + r31;  // 0..127 = gate*32 + h-in
      const int ng = ((n_loc >> 5) << 10) + h0 + (n_loc & 31);
      const u16* wp = Whp + ng * 1024 + kh * 256 + l5 * 8;
#pragma unroll
      for (int ks = 0; ks < 16; ++ks) breg[ks * 2 + nb] = *(const bf16x8*)(wp + ks * 16);
    }
  }

  // per-lane A-fragment offset into an h slot (u16 units), invariant across steps:
  // elem (m,k) lives at (k>>5)*4096 + m*32 + (k&31); wave reads k-quarter kh.
  const int voff = kh * 32768 + (m0 + r31) * 32 + l5 * 8;

  // cell ownership: thread -> (m = tid>>4, h pair = (tid&15)*2); c-state in regs
  const int cm = tid >> 4, ch2 = (tid & 15) << 1;
  const int mg = m0 + cm;
  float2 cp = *(const float2*)&cws[mg * 1024 + h0 + ch2];
  float c0v = cp.x, c1v = cp.y;

  for (int s = 0; s < 256; ++s) {
    const u16* hb = hring + s * 131072 + voff;  // this wave's frag base for step s
    u16* hout = hring + (s + 1) * 131072;

    if (tid == 0) {
      while (__hip_atomic_load(&g_gxrdy[s], __ATOMIC_RELAXED, __HIP_MEMORY_SCOPE_AGENT) < 32u)
        __builtin_amdgcn_s_sleep(1);
      const unsigned tgt = 32u * (unsigned)s;
      while (__hip_atomic_load(ctr, __ATOMIC_RELAXED, __HIP_MEMORY_SCOPE_AGENT) < tgt)
        __builtin_amdgcn_s_sleep(1);
    }
    __syncthreads();  // C: h[s] + gx[s] globally visible to everyone past here

    // gx prefetch (consumed in the cell update)
    const int gbase = (s * 128 + mg) * 4096 + h0 + ch2;
    const u32 gq0 = *(const u32*)(gx + gbase);
    const u32 gq1 = *(const u32*)(gx + gbase + 1024);
    const u32 gq2 = *(const u32*)(gx + gbase + 2048);
    const u32 gq3 = *(const u32*)(gx + gbase + 3072);

    // stream A-frags global->VGPR, 8 in flight; frag ks at (ks>>1)*4096 + (ks&1)*16
    f32x16 acc0 = {}, acc1 = {};
    bf16x8 av[8];
#pragma unroll
    for (int j = 0; j < 8; ++j)
      av[j] = *(const bf16x8*)(hb + ((j >> 1) << 12) + ((j & 1) << 4));
#pragma unroll
    for (int j = 0; j < 8; ++j) {
      const bf16x8 a = av[j];
      const int ks = 8 + j;
      av[j] = *(const bf16x8*)(hb + ((ks >> 1) << 12) + ((ks & 1) << 4));
      acc0 = __builtin_amdgcn_mfma_f32_32x32x16_bf16(a, breg[2 * j], acc0, 0, 0, 0);
      acc1 = __builtin_amdgcn_mfma_f32_32x32x16_bf16(a, breg[2 * j + 1], acc1, 0, 0, 0);
    }
#pragma unroll
    for (int j = 0; j < 8; ++j) {
      acc0 = __builtin_amdgcn_mfma_f32_32x32x16_bf16(av[j], breg[16 + 2 * j], acc0, 0, 0, 0);
      acc1 = __builtin_amdgcn_mfma_f32_32x32x16_bf16(av[j], breg[17 + 2 * j], acc1, 0, 0, 0);
    }

    // K-partial to LDS: C col = lane&31 (n), row m = (r&3)+8*(r>>2)+4*(lane>>5)
#pragma unroll
    for (int r = 0; r < 16; ++r) {
      const int m_l = (r & 3) + ((r >> 2) << 3) + (l5 << 2);
      pre[(kh * 128 + wn * 64 + r31) * 33 + m_l] = acc0[r];
      pre[(kh * 128 + wn * 64 + 32 + r31) * 33 + m_l] = acc1[r];
    }
    __syncthreads();  // A: all K-partials in LDS

    // fused cell update: 2 cells per thread (h pair), sum 4 K-partials + gates_x
    float p0[4], p1[4];
#pragma unroll
    for (int gi = 0; gi < 4; ++gi) {
      const int n0l = gi * 32 + ch2;
      p0[gi] = pre[n0l * 33 + cm] + pre[(128 + n0l) * 33 + cm] +
               pre[(256 + n0l) * 33 + cm] + pre[(384 + n0l) * 33 + cm];
      p1[gi] = pre[(n0l + 1) * 33 + cm] + pre[(128 + n0l + 1) * 33 + cm] +
               pre[(256 + n0l + 1) * 33 + cm] + pre[(384 + n0l + 1) * 33 + cm];
    }
    p0[0] += bf2f((u16)(gq0 & 0xffff)); p1[0] += bf2f((u16)(gq0 >> 16));
    p0[1] += bf2f((u16)(gq1 & 0xffff)); p1[1] += bf2f((u16)(gq1 >> 16));
    p0[2] += bf2f((u16)(gq2 & 0xffff)); p1[2] += bf2f((u16)(gq2 >> 16));
    p0[3] += bf2f((u16)(gq3 & 0xffff)); p1[3] += bf2f((u16)(gq3 >> 16));
    const float fg0 = sigm(p0[0]), ig0 = sigm(p0[1]), gg0 = tanh_f(p0[2]), og0 = sigm(p0[3]);
    const float fg1 = sigm(p1[0]), ig1 = sigm(p1[1]), gg1 = tanh_f(p1[2]), og1 = sigm(p1[3]);
    c0v = c0v * fg0 + ig0 * gg0;
    c1v = c1v * fg1 + ig1 * gg1;
    const float hn0 = tanh_f(c0v) * og0;
    const float hn1 = tanh_f(c1v) * og1;

    // coherent h store (one u32 = 2 bf16); must be LLC-visible before the bump
    __hip_atomic_store((u32*)(hout + hgrp * 4096 + mg * 32 + ch2), pack2bf(hn0, hn1),
                       __ATOMIC_RELAXED, __HIP_MEMORY_SCOPE_AGENT);
    asm volatile("s_waitcnt vmcnt(0)" ::: "memory");
    __syncthreads();  // B: whole block's h published
    if (tid == 0)
      __hip_atomic_fetch_add(ctr, 1u, __ATOMIC_RELAXED, __HIP_MEMORY_SCOPE_AGENT);

    // out store AFTER the bump: off the cross-block critical path
    *(float2*)&out[(mg * 256 + s) * 1024 + h0 + ch2] = make_float2(hn0, hn1);
  }
  *(float2*)&cws[mg * 1024 + h0 + ch2] = make_float2(c0v, c1v);
}

// ---------------- launch ----------------

extern "C" void kernel_launch(void* const* d_in, const int* in_sizes, int n_in,
                              void* d_out, int out_size, void* d_ws, size_t ws_size,
                              hipStream_t stream) {
  const float* x   = (const float*)d_in[0];
  const float* Wf  = (const float*)d_in[1];
  const float* bf_ = (const float*)d_in[2];
  const float* Wi  = (const float*)d_in[3];
  const float* bi  = (const float*)d_in[4];
  const float* Wc  = (const float*)d_in[5];
  const float* bc  = (const float*)d_in[6];
  const float* Wo  = (const float*)d_in[7];
  const float* bo  = (const float*)d_in[8];
  float* out = (float*)d_out;
  char* ws = (char*)d_ws;

  const size_t NEEDED = 420233216;
  if (ws_size < NEEDED) return;  // fail cleanly (wrong output) instead of faulting

  u16*  Xc    = (u16*)(ws);
  u16*  Whp   = (u16*)(ws + 67108864);
  u16*  Wxp   = (u16*)(ws + 75497472);
  float* biasp = (float*)(ws + 83886080);
  float* cws  = (float*)(ws + 83902464);
  u16*  hring = (u16*)(ws + 84426752);    // 257 x 262144 B
  u16*  gx    = (u16*)(ws + 151797760);   // 256 MB

  hipMemsetAsync(ws + 83902464, 0, 524288, stream);  // cws = 0
  hipMemsetAsync(ws + 84426752, 0, 262144, stream);  // hring slot 0 = 0
  convert_x<<<16384, 256, 0, stream>>>(x, Xc);
  pack_w<<<2048, 256, 0, stream>>>(Wf, Wi, Wc, Wo, Whp, Wxp);
  pack_b<<<16, 256, 0, stream>>>(bf_, bi, bc, bo, biasp);  // also zeroes g_bars/g_gxrdy

  void* args[8];
  args[0] = (void*)&Whp;
  args[1] = (void*)&Wxp;
  args[2] = (void*)&Xc;
  args[3] = (void*)&biasp;
  args[4] = (void*)&gx;
  args[5] = (void*)&hring;
  args[6] = (void*)&cws;
  args[7] = (void*)&out;
  if (hipLaunchCooperativeKernel((const void*)lstm_fused, dim3(256), dim3(512),
                                 args, 0, stream) != hipSuccess) {
    // fallback: plain launch. 256 blocks, <=1/CU by resources => co-resident;
    // flag-based sync does not require more than co-residency.
    lstm_fused<<<dim3(256), dim3(512), 0, stream>>>(Whp, Wxp, Xc, biasp, gx, hring, cws, out);
  }
}